// Round 5
// baseline (242.670 us; speedup 1.0000x reference)
//
#include <hip/hip_runtime.h>
#include <math.h>
#include <stdint.h>

#define NCLS   80
#define NPTS   8400
#define KEEP   100
#define PRETOPK 5000
#define NB     8
#define THRBITS 0x3C23D70Au   // bits of 0.01f (scores are positive floats -> int-ordered)

#define TBS    256            // select_nms block size
#define NREG   33             // ceil(8400/256)
#define CAPF   512            // candidate cap (rank-sort domain)
#define NEEDF  192u           // selection target
#define MTX    128            // suppression-matrix size

__device__ __forceinline__ float sigmoidf_(float x) { return 1.0f / (1.0f + expf(-x)); }

__device__ __forceinline__ void level_of(int n, int& base, int& W, int& HW, float& s, int& lvl) {
    if (n < 6400)      { lvl = 0; base = n;        W = 80; HW = 6400; s = 8.f;  }
    else if (n < 8000) { lvl = 1; base = n - 6400; W = 40; HW = 1600; s = 16.f; }
    else               { lvl = 2; base = n - 8000; W = 20; HW = 400;  s = 32.f; }
}

// ---------------------------------------------------------------- decode boxes
__global__ void decode_boxes(const float* __restrict__ bb0,
                             const float* __restrict__ bb1,
                             const float* __restrict__ bb2,
                             float4* __restrict__ boxes) {
    int t = blockIdx.x * blockDim.x + threadIdx.x;
    if (t >= NB * NPTS) return;
    int b = t / NPTS, n = t - b * NPTS;
    int base, W, HW, lvl; float s;
    level_of(n, base, W, HW, s, lvl);
    const float* bb = (lvl == 0) ? bb0 : ((lvl == 1) ? bb1 : bb2);
    const float* p = bb + (size_t)b * 4 * HW + base;
    float v0 = p[0], v1 = p[HW], v2 = p[2 * HW], v3 = p[3 * HW];
    int y = base / W, x = base - y * W;
    float px = x * s, py = y * s;
    float cx = v0 * s + px, cy = v1 * s + py;
    float w = expf(v2) * s, h = expf(v3) * s;
    boxes[t] = make_float4(cx - w * 0.5f, cy - h * 0.5f, cx + w * 0.5f, cy + h * 0.5f);
}

__device__ __forceinline__ bool iou_gt(float4 a, float4 c) {
    float tlx = fmaxf(a.x, c.x), tly = fmaxf(a.y, c.y);
    float brx = fminf(a.z, c.z), bry = fminf(a.w, c.w);
    float w = fmaxf(brx - tlx, 0.f), h = fmaxf(bry - tly, 0.f);
    float inter = w * h;
    float a1 = (a.z - a.x) * (a.w - a.y);
    float a2 = (c.z - c.x) * (c.w - c.y);
    return inter / (a1 + a2 - inter + 1e-6f) > 0.65f;
}

// ---------------------------------------------------------------- bitonic (key desc, idx asc) for topk
__device__ void bitonic_kv(uint32_t* key, uint16_t* idx, int P, int tid, int nthr) {
    for (int k = 2; k <= P; k <<= 1) {
        for (int j = k >> 1; j > 0; j >>= 1) {
            __syncthreads();
            for (int i = tid; i < (P >> 1); i += nthr) {
                int pos = ((i & ~(j - 1)) << 1) | (i & (j - 1));
                int par = pos | j;
                uint32_t ka = key[pos], kb = key[par];
                uint16_t ia = idx[pos], ib = idx[par];
                bool aBefore = (ka > kb) || (ka == kb && ia < ib);
                bool desc = ((pos & k) == 0);
                if (desc ? !aBefore : aBefore) {
                    key[pos] = kb; key[par] = ka;
                    idx[pos] = ib; idx[par] = ia;
                }
            }
        }
    }
    __syncthreads();
}

// ---------------------------------------------------------------- wave-0 crossing scan
__device__ void scan_cross(const uint32_t* hist, int nb, uint32_t need, uint32_t cap,
                           uint32_t carry, uint32_t prefix, int shift, int level,
                           uint32_t* shr, int lane) {
    int foundBin = -1; uint32_t cAbove = 0, bCnt = 0;
    uint32_t run = carry;
    for (int hi = nb - 1; hi >= 0; hi -= 64) {
        int bin = hi - lane;
        uint32_t c = (bin >= 0) ? hist[bin] : 0u;
        uint32_t inc = c;
        #pragma unroll
        for (int d = 1; d < 64; d <<= 1) { uint32_t t = __shfl_up(inc, d); if (lane >= d) inc += t; }
        unsigned long long msk = __ballot((run + inc >= need) ? 1 : 0);
        if (msk) {
            int fl = (int)__ffsll(msk) - 1;
            uint32_t incF = __shfl(inc, fl);
            uint32_t cF   = __shfl(c, fl);
            foundBin = hi - fl;
            cAbove = run + incF - cF;
            bCnt = cF;
            break;
        }
        run += (uint32_t)__shfl(inc, 63);
    }
    if (lane == 0) {
        if (foundBin < 0) { shr[1] = 0u; shr[0] = 0u; }   // take-all: total < need
        else {
            uint32_t cntIncl = cAbove + bCnt;
            if (cntIncl <= cap) { shr[1] = 0u; shr[0] = prefix | ((uint32_t)foundBin << shift); }
            else if (level == 2) { shr[1] = 0u; shr[0] = (prefix | (uint32_t)foundBin) + 1u; } // exclude fat tie-bin (continuation recovers)
            else { shr[1] = 1u; shr[2] = prefix | ((uint32_t)foundBin << shift); shr[3] = cAbove; }
        }
    }
}

// ---------------------------------------------------------------- fused per-(b,c) select + sort + NMS
__global__ __launch_bounds__(TBS)
void select_nms(const float* __restrict__ cls0, const float* __restrict__ obj0,
                const float* __restrict__ cls1, const float* __restrict__ obj1,
                const float* __restrict__ cls2, const float* __restrict__ obj2,
                const float4* __restrict__ boxes,
                float* __restrict__ keptScore, float4* __restrict__ keptBox) {
    __shared__ uint32_t sHist[4096];                 // 16 KB
    __shared__ uint32_t cKey[CAPF];                  // 2 KB (unordered)
    __shared__ uint16_t cIdx[CAPF];                  // 1 KB
    __shared__ uint32_t sKeyS[CAPF];                 // 2 KB (sorted)
    __shared__ uint16_t sIdxS[CAPF];                 // 1 KB
    __shared__ float4   bBoxS[CAPF];                 // 8 KB
    __shared__ unsigned long long rowsL[MTX * 2];    // 2 KB
    __shared__ uint32_t shr[4];
    __shared__ unsigned long long sh64;

    int bc = blockIdx.x;
    int b = bc / NCLS, c = bc - b * NCLS;
    int tid = threadIdx.x, lane = tid & 63;

    // ---- phase 1: keygen into registers
    uint32_t rKey[NREG];
    #pragma unroll
    for (int i = 0; i < NREG; ++i) {
        int n = tid + i * TBS;
        uint32_t key = 0u;
        if (n < NPTS) {
            int base, W, HW, lvl; float s;
            level_of(n, base, W, HW, s, lvl);
            const float* clsP = (lvl == 0) ? cls0 : ((lvl == 1) ? cls1 : cls2);
            const float* objP = (lvl == 0) ? obj0 : ((lvl == 1) ? obj1 : obj2);
            float cv = clsP[((size_t)b * NCLS + c) * HW + base];
            float ov = objP[(size_t)b * HW + base];
            key = __float_as_uint(sigmoidf_(cv) * sigmoidf_(ov));
        }
        rKey[i] = key;
    }

    // ---- phase 2: exact radix threshold selection (need=192, cap=512)
    uint32_t prefix = 0, carry = 0, Tsel = 0;
    for (int level = 0;; ++level) {
        int shift = (level == 0) ? 18 : (level == 1 ? 6 : 0);
        int nb = (level == 2) ? 64 : 4096;
        __syncthreads();
        for (int i = tid; i < nb; i += TBS) sHist[i] = 0;
        __syncthreads();
        #pragma unroll
        for (int i = 0; i < NREG; ++i) {
            uint32_t k = rKey[i];
            if (k > THRBITS) {
                if (level == 0) atomicAdd(&sHist[k >> 18], 1u);
                else if (level == 1) { if ((k >> 18) == (prefix >> 18)) atomicAdd(&sHist[(k >> 6) & 0xFFFu], 1u); }
                else { if ((k >> 6) == (prefix >> 6)) atomicAdd(&sHist[k & 0x3Fu], 1u); }
            }
        }
        __syncthreads();
        if (tid < 64) scan_cross(sHist, nb, NEEDF, CAPF, carry, prefix, shift, level, shr, lane);
        __syncthreads();
        if (shr[1] == 0u) { Tsel = shr[0]; break; }
        prefix = shr[2]; carry = shr[3];
    }
    __syncthreads();
    if (tid == 0) shr[3] = 0u;
    __syncthreads();

    // ---- phase 3: compact (unordered)
    #pragma unroll
    for (int i = 0; i < NREG; ++i) {
        uint32_t k = rKey[i];
        if (k > THRBITS && k >= Tsel) {
            uint32_t s = atomicAdd(&shr[3], 1u);
            if (s < CAPF) { cKey[s] = k; cIdx[s] = (uint16_t)(tid + i * TBS); }
        }
    }
    __syncthreads();
    int cnt = (int)shr[3]; if (cnt > CAPF) cnt = CAPF;

    // ---- phase 4: rank-sort (desc, idx asc); 2 barriers total
    {
        uint32_t k0 = 0, k1 = 0; uint16_t i0 = 0, i1 = 0; int r0 = 0, r1 = 0;
        bool h0 = tid < cnt, h1 = tid + TBS < cnt;
        if (h0) { k0 = cKey[tid]; i0 = cIdx[tid]; }
        if (h1) { k1 = cKey[tid + TBS]; i1 = cIdx[tid + TBS]; }
        for (int j = 0; j < cnt; ++j) {
            uint32_t kj = cKey[j]; uint16_t ij = cIdx[j];   // broadcast read
            if (h0) r0 += (kj > k0) || (kj == k0 && ij < i0);
            if (h1) r1 += (kj > k1) || (kj == k1 && ij < i1);
        }
        __syncthreads();
        if (h0) { sKeyS[r0] = k0; sIdxS[r0] = i0; }
        if (h1) { sKeyS[r1] = k1; sIdxS[r1] = i1; }
        __syncthreads();
    }

    // ---- phase 5: gather candidate boxes
    for (int s = tid; s < cnt; s += TBS) bBoxS[s] = boxes[(size_t)b * NPTS + sIdxS[s]];
    __syncthreads();

    // ---- phase 6: suppression bitmatrix over first MTX sorted candidates
    int lim = (cnt < MTX) ? cnt : MTX;
    if (tid < lim) {
        float4 bi = bBoxS[tid];
        unsigned long long w0 = 0, w1 = 0;
        for (int j = tid + 1; j < lim; ++j) {
            if (iou_gt(bBoxS[j], bi)) {
                if (j < 64) w0 |= 1ull << j; else w1 |= 1ull << (j - 64);
            }
        }
        rowsL[tid * 2] = w0; rowsL[tid * 2 + 1] = w1;
    }
    __syncthreads();

    // ---- phase 7: serial walk (wave 0): ffs-jump over unsuppressed bits
    float4 kb0 = make_float4(0.f, 0.f, 0.f, 0.f), kb1 = kb0;
    float ks0 = -1.0f, ks1 = -1.0f;
    int K = 0;
    if (tid < 64) {
        unsigned long long U0, U1;
        if (lim >= 64) { U0 = ~0ull; U1 = (lim >= 128) ? ~0ull : ((lim > 64) ? ((1ull << (lim - 64)) - 1) : 0ull); }
        else           { U0 = (lim > 0) ? ((1ull << lim) - 1) : 0ull; U1 = 0ull; }
        while (K < KEEP) {
            int i;
            if (U0) i = __ffsll(U0) - 1;
            else if (U1) i = 64 + (int)__ffsll(U1) - 1;
            else break;
            unsigned long long r0 = rowsL[i * 2], r1 = rowsL[i * 2 + 1];   // broadcast
            float sc = __uint_as_float(sKeyS[i]);
            float4 bx = bBoxS[i];
            if (i < 64) U0 &= ~(1ull << i); else U1 &= ~(1ull << (i - 64));
            U0 &= ~r0; U1 &= ~r1;
            if (K < 64) { if (lane == K)      { kb0 = bx; ks0 = sc; } }
            else        { if (lane == K - 64) { kb1 = bx; ks1 = sc; } }
            K++;
        }
        // mid-walk: candidates beyond the matrix (lim..cnt), exact order
        for (int i = lim; i < cnt && K < KEEP; ++i) {
            float4 bx = bBoxS[i];
            bool sup = false;
            if (lane < K)      sup = iou_gt(bx, kb0);
            if (64 + lane < K) sup = sup || iou_gt(bx, kb1);
            if (!__any(sup ? 1 : 0)) {
                float sc = __uint_as_float(sKeyS[i]);
                if (K < 64) { if (lane == K)      { kb0 = bx; ks0 = sc; } }
                else        { if (lane == K - 64) { kb1 = bx; ks1 = sc; } }
                K++;
            }
        }
        if (lane == 0) {
            shr[0] = (uint32_t)K;
            shr[1] = (uint32_t)cnt;                          // positions consumed so far
            shr[2] = (cnt > 0) ? sKeyS[cnt - 1] : 0xFFFFFFFFu;
            shr[3] = (cnt > 0) ? (uint32_t)sIdxS[cnt - 1] : 0xFFFFFFFFu;
        }
    }
    __syncthreads();
    int Kall = (int)shr[0]; int e = (int)shr[1];
    uint32_t cK = shr[2], cI = shr[3];

    // ---- phase 8: exact continuation via block argmax (rare)
    if (Kall < KEEP && e < PRETOPK) {
        for (;;) {
            if (tid == 0) sh64 = 0ull;
            __syncthreads();
            unsigned long long best = 0ull;
            #pragma unroll
            for (int i = 0; i < NREG; ++i) {
                uint32_t k = rKey[i]; int n = tid + i * TBS;
                if (k > THRBITS && (k < cK || (k == cK && (uint32_t)n > cI))) {
                    unsigned long long v = ((unsigned long long)k << 32) | (unsigned long long)(NPTS - 1 - n);
                    if (v > best) best = v;
                }
            }
            if (best) atomicMax(&sh64, best);
            __syncthreads();
            unsigned long long bv = sh64;
            if (bv == 0ull) break;
            uint32_t k = (uint32_t)(bv >> 32);
            int n = NPTS - 1 - (int)(bv & 0xFFFFFFFFull);
            if (tid < 64) {
                float4 bx = boxes[(size_t)b * NPTS + n];
                bool sup = false;
                if (lane < K)      sup = iou_gt(bx, kb0);
                if (64 + lane < K) sup = sup || iou_gt(bx, kb1);
                if (!__any(sup ? 1 : 0)) {
                    float sc = __uint_as_float(k);
                    if (K < 64) { if (lane == K)      { kb0 = bx; ks0 = sc; } }
                    else        { if (lane == K - 64) { kb1 = bx; ks1 = sc; } }
                    K++;
                }
                if (lane == 0) shr[0] = (uint32_t)K;
            }
            __syncthreads();
            Kall = (int)shr[0];
            e++; cK = k; cI = (uint32_t)n;
            if (Kall >= KEEP || e >= PRETOPK) break;
        }
    }

    // ---- output
    if (tid < 64) {
        int off = (b * NCLS + c) * KEEP;
        float4 z = make_float4(0.f, 0.f, 0.f, 0.f);
        keptScore[off + lane] = (lane < K) ? ks0 : -1.0f;
        keptBox[off + lane]   = (lane < K) ? kb0 : z;
        if (64 + lane < KEEP) {
            keptScore[off + 64 + lane] = (64 + lane < K) ? ks1 : -1.0f;
            keptBox[off + 64 + lane]   = (64 + lane < K) ? kb1 : z;
        }
    }
}

// ---------------------------------------------------------------- topk stage A: per (image, 10-class chunk) top-100
__global__ __launch_bounds__(256)
void topk_a(const float* __restrict__ keptScore,
            uint32_t* __restrict__ tkKey, uint32_t* __restrict__ tkIdx) {
    __shared__ uint32_t tKey[1024];
    __shared__ uint16_t tIdx[1024];
    int bc = blockIdx.x;
    int b = bc >> 3, ch = bc & 7;
    int tid = threadIdx.x;

    for (int i = tid; i < 1024; i += 256) {
        uint32_t key = 0u; uint16_t id = 0xFFFF;
        if (i < 1000) {
            float s = keptScore[b * (NCLS * KEEP) + ch * 1000 + i];
            key = (s > 0.f) ? __float_as_uint(s) : 0u;
            id = (uint16_t)i;
        }
        tKey[i] = key; tIdx[i] = id;
    }
    bitonic_kv(tKey, tIdx, 1024, tid, 256);

    if (tid < KEEP) {
        uint32_t key = tKey[tid];
        uint32_t fi = (key > 0u) ? (uint32_t)(ch * 1000 + (int)tIdx[tid]) : 0u;
        tkKey[bc * KEEP + tid] = key;
        tkIdx[bc * KEEP + tid] = fi;
    }
}

// ---------------------------------------------------------------- topk stage B: per image top-100 of 800 + output
__global__ __launch_bounds__(256)
void topk_b(const uint32_t* __restrict__ tkKey, const uint32_t* __restrict__ tkIdx,
            const float4* __restrict__ keptBox, float* __restrict__ out) {
    __shared__ uint32_t tKey[1024];
    __shared__ uint16_t tIdx[1024];
    __shared__ int cnt;
    int b = blockIdx.x, tid = threadIdx.x;
    const int TOT = NCLS * KEEP;

    for (int i = tid; i < 1024; i += 256) {
        uint32_t key = 0u; uint16_t id = 0xFFFF;
        if (i < 800) {
            key = tkKey[b * 800 + i];
            id = (uint16_t)tkIdx[b * 800 + i];   // flat index 0..7999: global tie-break order
        }
        tKey[i] = key; tIdx[i] = id;
    }
    if (tid == 0) cnt = 0;
    bitonic_kv(tKey, tIdx, 1024, tid, 256);

    if (tid < KEEP) {
        uint32_t key = tKey[tid];
        bool valid = key > 0u;
        int fi = valid ? (int)tIdx[tid] : 0;
        float sc = valid ? __uint_as_float(key) : 0.f;
        float4 bx = valid ? keptBox[b * TOT + fi] : make_float4(0.f, 0.f, 0.f, 0.f);
        float cls = valid ? (float)(fi / KEEP) : -1.0f;
        float* boxOut = out + NB + (b * KEEP + tid) * 4;
        boxOut[0] = bx.x; boxOut[1] = bx.y; boxOut[2] = bx.z; boxOut[3] = bx.w;
        out[NB + NB * KEEP * 4 + b * KEEP + tid] = sc;
        out[NB + NB * KEEP * 4 + NB * KEEP + b * KEEP + tid] = cls;
        if (valid) atomicAdd(&cnt, 1);
    }
    __syncthreads();
    if (tid == 0) out[b] = (float)cnt;
}

// ---------------------------------------------------------------- launch
extern "C" void kernel_launch(void* const* d_in, const int* in_sizes, int n_in,
                              void* d_out, int out_size, void* d_ws, size_t ws_size,
                              hipStream_t stream) {
    const float* cls0 = (const float*)d_in[0];
    const float* bb0  = (const float*)d_in[1];
    const float* obj0 = (const float*)d_in[2];
    const float* cls1 = (const float*)d_in[3];
    const float* bb1  = (const float*)d_in[4];
    const float* obj1 = (const float*)d_in[5];
    const float* cls2 = (const float*)d_in[6];
    const float* bb2  = (const float*)d_in[7];
    const float* obj2 = (const float*)d_in[8];
    float* out = (float*)d_out;

    char* ws = (char*)d_ws;
    float4*   boxes     = (float4*)(ws);                 // 1,075,200 B
    float*    keptScore = (float*)(ws + 1075200);        //   256,000 B
    float4*   keptBox   = (float4*)(ws + 1331200);       // 1,024,000 B
    uint32_t* tkKey     = (uint32_t*)(ws + 2355200);     //    25,600 B
    uint32_t* tkIdx     = (uint32_t*)(ws + 2380800);     //    25,600 B

    decode_boxes<<<(NB * NPTS + 255) / 256, 256, 0, stream>>>(bb0, bb1, bb2, boxes);
    select_nms<<<NB * NCLS, TBS, 0, stream>>>(cls0, obj0, cls1, obj1, cls2, obj2,
                                              boxes, keptScore, keptBox);
    topk_a<<<NB * 8, 256, 0, stream>>>(keptScore, tkKey, tkIdx);
    topk_b<<<NB, 256, 0, stream>>>(tkKey, tkIdx, keptBox, out);
}

// Round 6
// 215.695 us; speedup vs baseline: 1.1251x; 1.1251x over previous
//
#include <hip/hip_runtime.h>
#include <math.h>
#include <stdint.h>

#define NCLS   80
#define NPTS   8400
#define KEEP   100
#define PRETOPK 5000
#define NB     8
#define THRBITS 0x3C23D70Au   // bits of 0.01f (scores are positive floats -> int-ordered)

#define TBS    512            // select_nms block size
#define NREG   17             // ceil(8400/512)
#define CAPF   512            // candidate cap
#define NEEDF  192u           // selection target
#define MTX    128            // suppression-matrix size

#define TBT    1024           // topk block size
#define NREGT  8              // 8000/1024
#define CAPT   512

__device__ __forceinline__ float sigmoidf_(float x) { return 1.0f / (1.0f + expf(-x)); }

__device__ __forceinline__ void level_of(int n, int& base, int& W, int& HW, float& s, int& lvl) {
    if (n < 6400)      { lvl = 0; base = n;        W = 80; HW = 6400; s = 8.f;  }
    else if (n < 8000) { lvl = 1; base = n - 6400; W = 40; HW = 1600; s = 16.f; }
    else               { lvl = 2; base = n - 8000; W = 20; HW = 400;  s = 32.f; }
}

__device__ __forceinline__ unsigned long long shfl_u64_(unsigned long long v, int src) {
    int lo = __shfl((int)(uint32_t)v, src);
    int hi = __shfl((int)(uint32_t)(v >> 32), src);
    return ((unsigned long long)(uint32_t)hi << 32) | (uint32_t)lo;
}

// ---------------------------------------------------------------- decode boxes
__global__ void decode_boxes(const float* __restrict__ bb0,
                             const float* __restrict__ bb1,
                             const float* __restrict__ bb2,
                             float4* __restrict__ boxes) {
    int t = blockIdx.x * blockDim.x + threadIdx.x;
    if (t >= NB * NPTS) return;
    int b = t / NPTS, n = t - b * NPTS;
    int base, W, HW, lvl; float s;
    level_of(n, base, W, HW, s, lvl);
    const float* bb = (lvl == 0) ? bb0 : ((lvl == 1) ? bb1 : bb2);
    const float* p = bb + (size_t)b * 4 * HW + base;
    float v0 = p[0], v1 = p[HW], v2 = p[2 * HW], v3 = p[3 * HW];
    int y = base / W, x = base - y * W;
    float px = x * s, py = y * s;
    float cx = v0 * s + px, cy = v1 * s + py;
    float w = expf(v2) * s, h = expf(v3) * s;
    boxes[t] = make_float4(cx - w * 0.5f, cy - h * 0.5f, cx + w * 0.5f, cy + h * 0.5f);
}

__device__ __forceinline__ bool iou_gt(float4 a, float4 c) {
    float tlx = fmaxf(a.x, c.x), tly = fmaxf(a.y, c.y);
    float brx = fminf(a.z, c.z), bry = fminf(a.w, c.w);
    float w = fmaxf(brx - tlx, 0.f), h = fmaxf(bry - tly, 0.f);
    float inter = w * h;
    float a1 = (a.z - a.x) * (a.w - a.y);
    float a2 = (c.z - c.x) * (c.w - c.y);
    return inter / (a1 + a2 - inter + 1e-6f) > 0.65f;
}

// ---------------------------------------------------------------- parallel crossing scan (wave 0 only)
// Finds topmost bin where cumulative-from-top (+carry) crosses `need`.
// shr[1]=1 -> refine (shr[2]=prefix', shr[3]=carry'); shr[1]=0 -> done (shr[0]=Tsel).
__device__ void scan_cross_fast(const uint32_t* hist, int nb, uint32_t need, uint32_t cap,
                                uint32_t carry, uint32_t prefix, int shift, int level,
                                uint32_t* shr, int lane) {
    uint32_t csum;
    if (nb == 4096) {
        uint32_t s = 0;
        int cb = lane << 6;
        #pragma unroll 8
        for (int i = 0; i < 64; ++i) s += hist[cb + i];
        csum = s;
    } else {
        csum = hist[lane];
    }
    uint32_t suf = csum;                      // inclusive suffix sum over lanes
    #pragma unroll
    for (int d = 1; d < 64; d <<= 1) {
        uint32_t t = (uint32_t)__shfl_down((int)suf, d);
        if (lane + d < 64) suf += t;
    }
    unsigned long long m = __ballot(carry + suf >= need);
    if (!m) { if (lane == 0) { shr[1] = 0u; shr[0] = 0u; } return; }   // take-all
    int l1 = 63 - __clzll(m);
    uint32_t sufL1 = (uint32_t)__shfl((int)suf, l1);
    uint32_t csumL1 = (uint32_t)__shfl((int)csum, l1);
    uint32_t carry2 = carry + sufL1 - csumL1;
    int foundBin; uint32_t cAbove, bCnt;
    if (nb == 4096) {
        int cb = l1 << 6;
        uint32_t c2 = hist[cb + lane];
        uint32_t suf2 = c2;
        #pragma unroll
        for (int d = 1; d < 64; d <<= 1) {
            uint32_t t = (uint32_t)__shfl_down((int)suf2, d);
            if (lane + d < 64) suf2 += t;
        }
        unsigned long long m2 = __ballot(carry2 + suf2 >= need);
        int l2 = 63 - __clzll(m2);
        foundBin = cb + l2;
        uint32_t suf2L = (uint32_t)__shfl((int)suf2, l2);
        uint32_t c2L = (uint32_t)__shfl((int)c2, l2);
        cAbove = carry2 + suf2L - c2L;
        bCnt = c2L;
    } else {
        foundBin = l1;
        cAbove = carry2;
        bCnt = csumL1;
    }
    if (lane == 0) {
        uint32_t cntIncl = cAbove + bCnt;
        if (cntIncl <= cap) { shr[1] = 0u; shr[0] = prefix | ((uint32_t)foundBin << shift); }
        else if (level == 2) { shr[1] = 0u; shr[0] = (prefix | (uint32_t)foundBin) + 1u; }  // exclude fat tie-bin (continuation recovers)
        else { shr[1] = 1u; shr[2] = prefix | ((uint32_t)foundBin << shift); shr[3] = cAbove; }
    }
}

// ---------------------------------------------------------------- fused per-(b,c) select + sort + NMS
__global__ __launch_bounds__(TBS)
void select_nms(const float* __restrict__ cls0, const float* __restrict__ obj0,
                const float* __restrict__ cls1, const float* __restrict__ obj1,
                const float* __restrict__ cls2, const float* __restrict__ obj2,
                const float4* __restrict__ boxes,
                float* __restrict__ keptScore, float4* __restrict__ keptBox) {
    __shared__ uint32_t sHist[4096];                 // 16 KB
    __shared__ uint32_t cKey[CAPF];                  // 2 KB (unordered)
    __shared__ uint16_t cIdx[CAPF];                  // 1 KB
    __shared__ uint32_t sKeyS[CAPF];                 // 2 KB (sorted)
    __shared__ uint16_t sIdxS[CAPF];                 // 1 KB
    __shared__ float4   bBoxS[CAPF];                 // 8 KB
    __shared__ unsigned long long rowsL[MTX * 2];    // 2 KB
    __shared__ uint32_t shr[4];
    __shared__ unsigned long long sh64;

    int bc = blockIdx.x;
    int b = bc / NCLS, c = bc - b * NCLS;
    int tid = threadIdx.x, lane = tid & 63;

    // ---- phase 1: keygen into registers
    uint32_t rKey[NREG];
    #pragma unroll
    for (int i = 0; i < NREG; ++i) {
        int n = tid + i * TBS;
        uint32_t key = 0u;
        if (n < NPTS) {
            int base, W, HW, lvl; float s;
            level_of(n, base, W, HW, s, lvl);
            const float* clsP = (lvl == 0) ? cls0 : ((lvl == 1) ? cls1 : cls2);
            const float* objP = (lvl == 0) ? obj0 : ((lvl == 1) ? obj1 : obj2);
            float cv = clsP[((size_t)b * NCLS + c) * HW + base];
            float ov = objP[(size_t)b * HW + base];
            key = __float_as_uint(sigmoidf_(cv) * sigmoidf_(ov));
        }
        rKey[i] = key;
    }

    // ---- phase 2: exact radix threshold selection
    uint32_t prefix = 0, carry = 0, Tsel = 0;
    for (int level = 0;; ++level) {
        int shift = (level == 0) ? 18 : (level == 1 ? 6 : 0);
        int nb = (level == 2) ? 64 : 4096;
        __syncthreads();
        for (int i = tid; i < nb; i += TBS) sHist[i] = 0;
        __syncthreads();
        #pragma unroll
        for (int i = 0; i < NREG; ++i) {
            uint32_t k = rKey[i];
            if (k > THRBITS) {
                if (level == 0) atomicAdd(&sHist[k >> 18], 1u);
                else if (level == 1) { if ((k >> 18) == (prefix >> 18)) atomicAdd(&sHist[(k >> 6) & 0xFFFu], 1u); }
                else { if ((k >> 6) == (prefix >> 6)) atomicAdd(&sHist[k & 0x3Fu], 1u); }
            }
        }
        __syncthreads();
        if (tid < 64) scan_cross_fast(sHist, nb, NEEDF, CAPF, carry, prefix, shift, level, shr, lane);
        __syncthreads();
        if (shr[1] == 0u) { Tsel = shr[0]; break; }
        prefix = shr[2]; carry = shr[3];
    }
    __syncthreads();
    if (tid == 0) shr[3] = 0u;
    __syncthreads();

    // ---- phase 3: compact (unordered)
    #pragma unroll
    for (int i = 0; i < NREG; ++i) {
        uint32_t k = rKey[i];
        if (k > THRBITS && k >= Tsel) {
            uint32_t s = atomicAdd(&shr[3], 1u);
            if (s < CAPF) { cKey[s] = k; cIdx[s] = (uint16_t)(tid + i * TBS); }
        }
    }
    __syncthreads();
    int cnt = (int)shr[3]; if (cnt > CAPF) cnt = CAPF;

    // ---- phase 4: rank-sort (desc, idx asc)
    {
        uint32_t k0 = 0; uint16_t i0 = 0; int r0 = 0;
        bool h0 = tid < cnt;
        if (h0) { k0 = cKey[tid]; i0 = cIdx[tid]; }
        for (int j = 0; j < cnt; ++j) {
            uint32_t kj = cKey[j]; uint16_t ij = cIdx[j];   // broadcast
            if (h0) r0 += (kj > k0) || (kj == k0 && ij < i0);
        }
        __syncthreads();
        if (h0) { sKeyS[r0] = k0; sIdxS[r0] = i0; }
        __syncthreads();
    }

    // ---- phase 5: gather candidate boxes
    for (int s = tid; s < cnt; s += TBS) bBoxS[s] = boxes[(size_t)b * NPTS + sIdxS[s]];
    __syncthreads();

    // ---- phase 6: suppression bitmatrix over first MTX sorted candidates
    int lim = (cnt < MTX) ? cnt : MTX;
    if (tid < lim) {
        float4 bi = bBoxS[tid];
        unsigned long long w0 = 0, w1 = 0;
        for (int j = tid + 1; j < lim; ++j) {
            if (iou_gt(bBoxS[j], bi)) {
                if (j < 64) w0 |= 1ull << j; else w1 |= 1ull << (j - 64);
            }
        }
        rowsL[tid * 2] = w0; rowsL[tid * 2 + 1] = w1;
    }
    __syncthreads();

    // ---- phase 7: serial walk (wave 0), rows/keys/boxes register-resident
    float4 kb0 = make_float4(0.f, 0.f, 0.f, 0.f), kb1 = kb0;
    float ks0 = -1.0f, ks1 = -1.0f;
    int K = 0;
    if (tid < 64) {
        unsigned long long rA0 = 0, rA1 = 0, rB0 = 0, rB1 = 0;
        uint32_t kA = 0, kB = 0;
        float4 bA = make_float4(0.f, 0.f, 0.f, 0.f), bB = bA;
        if (lane < lim)      { rA0 = rowsL[lane * 2]; rA1 = rowsL[lane * 2 + 1]; kA = sKeyS[lane]; bA = bBoxS[lane]; }
        if (64 + lane < lim) { rB0 = rowsL[(64 + lane) * 2]; rB1 = rowsL[(64 + lane) * 2 + 1]; kB = sKeyS[64 + lane]; bB = bBoxS[64 + lane]; }
        unsigned long long U0, U1;
        if (lim >= 64) { U0 = ~0ull; U1 = (lim >= 128) ? ~0ull : ((lim > 64) ? ((1ull << (lim - 64)) - 1) : 0ull); }
        else           { U0 = (lim > 0) ? ((1ull << lim) - 1) : 0ull; U1 = 0ull; }
        while (K < KEEP) {
            int i;
            if (U0) i = __ffsll(U0) - 1;
            else if (U1) i = 64 + (int)__ffsll(U1) - 1;
            else break;
            int il = i & 63;
            unsigned long long r0, r1; float4 bx; float sc;
            if (i < 64) {
                r0 = shfl_u64_(rA0, il); r1 = shfl_u64_(rA1, il);
                bx.x = __shfl(bA.x, il); bx.y = __shfl(bA.y, il);
                bx.z = __shfl(bA.z, il); bx.w = __shfl(bA.w, il);
                sc = __uint_as_float((uint32_t)__shfl((int)kA, il));
                U0 &= ~(1ull << i);
            } else {
                r0 = shfl_u64_(rB0, il); r1 = shfl_u64_(rB1, il);
                bx.x = __shfl(bB.x, il); bx.y = __shfl(bB.y, il);
                bx.z = __shfl(bB.z, il); bx.w = __shfl(bB.w, il);
                sc = __uint_as_float((uint32_t)__shfl((int)kB, il));
                U1 &= ~(1ull << (i - 64));
            }
            U0 &= ~r0; U1 &= ~r1;
            if (K < 64) { if (lane == K)      { kb0 = bx; ks0 = sc; } }
            else        { if (lane == K - 64) { kb1 = bx; ks1 = sc; } }
            K++;
        }
        // mid-walk: candidates beyond the matrix (lim..cnt), exact order
        for (int i = lim; i < cnt && K < KEEP; ++i) {
            float4 bx = bBoxS[i];
            bool sup = false;
            if (lane < K)      sup = iou_gt(bx, kb0);
            if (64 + lane < K) sup = sup || iou_gt(bx, kb1);
            if (!__any(sup ? 1 : 0)) {
                float sc = __uint_as_float(sKeyS[i]);
                if (K < 64) { if (lane == K)      { kb0 = bx; ks0 = sc; } }
                else        { if (lane == K - 64) { kb1 = bx; ks1 = sc; } }
                K++;
            }
        }
        if (lane == 0) {
            shr[0] = (uint32_t)K;
            shr[1] = (uint32_t)cnt;
            shr[2] = (cnt > 0) ? sKeyS[cnt - 1] : 0xFFFFFFFFu;
            shr[3] = (cnt > 0) ? (uint32_t)sIdxS[cnt - 1] : 0xFFFFFFFFu;
        }
    }
    __syncthreads();
    int Kall = (int)shr[0]; int e = (int)shr[1];
    uint32_t cK = shr[2], cI = shr[3];

    // ---- phase 8: exact continuation via block argmax (rare)
    if (Kall < KEEP && e < PRETOPK) {
        for (;;) {
            if (tid == 0) sh64 = 0ull;
            __syncthreads();
            unsigned long long best = 0ull;
            #pragma unroll
            for (int i = 0; i < NREG; ++i) {
                uint32_t k = rKey[i]; int n = tid + i * TBS;
                if (k > THRBITS && (k < cK || (k == cK && (uint32_t)n > cI))) {
                    unsigned long long v = ((unsigned long long)k << 32) | (unsigned long long)(NPTS - 1 - n);
                    if (v > best) best = v;
                }
            }
            if (best) atomicMax(&sh64, best);
            __syncthreads();
            unsigned long long bv = sh64;
            if (bv == 0ull) break;
            uint32_t k = (uint32_t)(bv >> 32);
            int n = NPTS - 1 - (int)(bv & 0xFFFFFFFFull);
            if (tid < 64) {
                float4 bx = boxes[(size_t)b * NPTS + n];
                bool sup = false;
                if (lane < K)      sup = iou_gt(bx, kb0);
                if (64 + lane < K) sup = sup || iou_gt(bx, kb1);
                if (!__any(sup ? 1 : 0)) {
                    float sc = __uint_as_float(k);
                    if (K < 64) { if (lane == K)      { kb0 = bx; ks0 = sc; } }
                    else        { if (lane == K - 64) { kb1 = bx; ks1 = sc; } }
                    K++;
                }
                if (lane == 0) shr[0] = (uint32_t)K;
            }
            __syncthreads();
            Kall = (int)shr[0];
            e++; cK = k; cI = (uint32_t)n;
            if (Kall >= KEEP || e >= PRETOPK) break;
        }
    }

    // ---- output
    if (tid < 64) {
        int off = (b * NCLS + c) * KEEP;
        float4 z = make_float4(0.f, 0.f, 0.f, 0.f);
        keptScore[off + lane] = (lane < K) ? ks0 : -1.0f;
        keptBox[off + lane]   = (lane < K) ? kb0 : z;
        if (64 + lane < KEEP) {
            keptScore[off + 64 + lane] = (64 + lane < K) ? ks1 : -1.0f;
            keptBox[off + 64 + lane]   = (64 + lane < K) ? kb1 : z;
        }
    }
}

// ---------------------------------------------------------------- fused per-image top-100 + output
__global__ __launch_bounds__(TBT)
void topk_out(const float* __restrict__ keptScore, const float4* __restrict__ keptBox,
              float* __restrict__ out) {
    __shared__ uint32_t sHist[4096];                 // 16 KB
    __shared__ uint32_t cKey[CAPT];                  // 2 KB
    __shared__ uint16_t cIdx[CAPT];                  // 1 KB
    __shared__ uint32_t sKeyS[CAPT];                 // 2 KB
    __shared__ uint16_t sIdxS[CAPT];                 // 1 KB
    __shared__ uint32_t shr[4];
    int b = blockIdx.x, tid = threadIdx.x, lane = tid & 63;
    const int TOT = NCLS * KEEP;                     // 8000

    uint32_t rKey[NREGT];
    #pragma unroll
    for (int i = 0; i < NREGT; ++i) {
        int n = tid + i * TBT;
        uint32_t key = 0u;
        if (n < TOT) {
            float s = keptScore[b * TOT + n];
            key = (s > 0.f) ? __float_as_uint(s) : 0u;
        }
        rKey[i] = key;
    }

    uint32_t prefix = 0, carry = 0, Tsel = 0;
    for (int level = 0;; ++level) {
        int shift = (level == 0) ? 18 : (level == 1 ? 6 : 0);
        int nb = (level == 2) ? 64 : 4096;
        __syncthreads();
        for (int i = tid; i < nb; i += TBT) sHist[i] = 0;
        __syncthreads();
        #pragma unroll
        for (int i = 0; i < NREGT; ++i) {
            uint32_t k = rKey[i];
            if (k > 0u) {
                if (level == 0) atomicAdd(&sHist[k >> 18], 1u);
                else if (level == 1) { if ((k >> 18) == (prefix >> 18)) atomicAdd(&sHist[(k >> 6) & 0xFFFu], 1u); }
                else { if ((k >> 6) == (prefix >> 6)) atomicAdd(&sHist[k & 0x3Fu], 1u); }
            }
        }
        __syncthreads();
        if (tid < 64) scan_cross_fast(sHist, nb, (uint32_t)KEEP, CAPT, carry, prefix, shift, level, shr, lane);
        __syncthreads();
        if (shr[1] == 0u) { Tsel = shr[0]; break; }
        prefix = shr[2]; carry = shr[3];
    }
    __syncthreads();
    if (tid == 0) shr[3] = 0u;
    __syncthreads();
    #pragma unroll
    for (int i = 0; i < NREGT; ++i) {
        uint32_t k = rKey[i];
        if (k > 0u && k >= Tsel) {
            uint32_t s = atomicAdd(&shr[3], 1u);
            if (s < CAPT) { cKey[s] = k; cIdx[s] = (uint16_t)(tid + i * TBT); }
        }
    }
    __syncthreads();
    int cnt = (int)shr[3]; if (cnt > CAPT) cnt = CAPT;

    // rank-sort (desc, flat idx asc — matches lax.top_k tie rule)
    {
        uint32_t k0 = 0; uint16_t i0 = 0; int r0 = 0;
        bool h0 = tid < cnt;
        if (h0) { k0 = cKey[tid]; i0 = cIdx[tid]; }
        for (int j = 0; j < cnt; ++j) {
            uint32_t kj = cKey[j]; uint16_t ij = cIdx[j];
            if (h0) r0 += (kj > k0) || (kj == k0 && ij < i0);
        }
        __syncthreads();
        if (h0) { sKeyS[r0] = k0; sIdxS[r0] = i0; }
        __syncthreads();
    }

    if (tid < KEEP) {
        bool valid = tid < cnt;
        int fi = valid ? (int)sIdxS[tid] : 0;
        float sc = valid ? __uint_as_float(sKeyS[tid]) : 0.f;
        float4 bx = valid ? keptBox[b * TOT + fi] : make_float4(0.f, 0.f, 0.f, 0.f);
        float cls = valid ? (float)(fi / KEEP) : -1.0f;
        float* boxOut = out + NB + (b * KEEP + tid) * 4;
        boxOut[0] = bx.x; boxOut[1] = bx.y; boxOut[2] = bx.z; boxOut[3] = bx.w;
        out[NB + NB * KEEP * 4 + b * KEEP + tid] = sc;
        out[NB + NB * KEEP * 4 + NB * KEEP + b * KEEP + tid] = cls;
    }
    if (tid == 0) out[b] = (float)((cnt < KEEP) ? cnt : KEEP);
}

// ---------------------------------------------------------------- launch
extern "C" void kernel_launch(void* const* d_in, const int* in_sizes, int n_in,
                              void* d_out, int out_size, void* d_ws, size_t ws_size,
                              hipStream_t stream) {
    const float* cls0 = (const float*)d_in[0];
    const float* bb0  = (const float*)d_in[1];
    const float* obj0 = (const float*)d_in[2];
    const float* cls1 = (const float*)d_in[3];
    const float* bb1  = (const float*)d_in[4];
    const float* obj1 = (const float*)d_in[5];
    const float* cls2 = (const float*)d_in[6];
    const float* bb2  = (const float*)d_in[7];
    const float* obj2 = (const float*)d_in[8];
    float* out = (float*)d_out;

    char* ws = (char*)d_ws;
    float4* boxes     = (float4*)(ws);                 // 1,075,200 B
    float*  keptScore = (float*)(ws + 1075200);        //   256,000 B
    float4* keptBox   = (float4*)(ws + 1331200);       // 1,024,000 B

    decode_boxes<<<(NB * NPTS + 255) / 256, 256, 0, stream>>>(bb0, bb1, bb2, boxes);
    select_nms<<<NB * NCLS, TBS, 0, stream>>>(cls0, obj0, cls1, obj1, cls2, obj2,
                                              boxes, keptScore, keptBox);
    topk_out<<<NB, TBT, 0, stream>>>(keptScore, keptBox, out);
}